// Round 3
// baseline (88.652 us; speedup 1.0000x reference)
//
#include <hip/hip_runtime.h>

// Problem constants
#define NH 64
#define NW 64
#define ND 32
#define LTOT (NH * NW * ND)   // 131072

// Symmetric-pair formulation (verified exact in R2):
//   loss * L = sum_{unordered in-bounds pairs (p,q), 7x7x3 nbhd} 2*k_pq*(1 - y0p*y0q - y1p*y1q)
//            + sum_p (147 - nh*nw*nd) * k_oob(p)
// k_oob(p) = exp(-0.5*||center feats||^2)  (zero-padded unfold semantics).
// 73 half-offsets = 24 (dh,dw) pairs x dd in {-1,0,1}  +  the lone (0,0,1).

// Prep: pack (y0, y1, 10*sample, 0) per voxel -> one dwordx4 load per tap.
__global__ __launch_bounds__(256)
void pack_kernel(const float* __restrict__ y, const float* __restrict__ sample,
                 float4* __restrict__ ws4)
{
    const int p = blockIdx.x * 256 + threadIdx.x;
    ws4[p] = make_float4(y[p], y[LTOT + p], sample[p] * 10.0f, 0.0f);
}

__global__ __launch_bounds__(512, 4)
void gatedcrf3d_kernel(const float4* __restrict__ ws4,
                       const float* __restrict__ spacing, // (3,)
                       float* __restrict__ out)           // (1,) pre-zeroed
{
    const int tid = threadIdx.x;
    const int sub = tid >> 6;                         // wave-uniform, 0..7
    const int p   = blockIdx.x * 64 + (tid & 63);

    const int d = p & (ND - 1);
    const int w = (p >> 5) & (NW - 1);
    const int h = p >> 11;

    const float sH = spacing[0] * 0.2f;               // / SIGMA_XY
    const float sW = spacing[1] * 0.2f;
    const float sD = spacing[2] * 0.2f;
    const float nh2 = -0.5f * sH * sH;                // pre-scaled by -0.5
    const float nw2 = -0.5f * sW * sW;
    const float nd2 = -0.5f * sD * sD;

    const float4 c = ws4[p];
    const float y0c = c.x, y1c = c.y, ic = c.z;       // ic already * 10

    float acc   = 0.0f;    // doubled later
    float extra = 0.0f;    // not doubled

    auto pair_body = [&](int dh, int dw) {
        const int hh = h + dh;
        const int ww = w + dw;
        const bool ibhw = ((unsigned)hh < NH) & ((unsigned)ww < NW);
        const int hc = min(max(hh, 0), NH - 1);
        const int wc = min(max(ww, 0), NW - 1);
        const int qb = (hc << 11) + (wc << 5);
        const float spatHW = nh2 * (float)(dh * dh) + nw2 * (float)(dw * dw);
        #pragma unroll
        for (int dd = -1; dd <= 1; ++dd) {
            const int zz = d + dd;
            const bool inb = ibhw & ((unsigned)zz < ND);
            const int zc = min(max(zz, 0), ND - 1);
            const float4 f = ws4[qb + zc];
            const float di = f.z - ic;
            const float spat = (dd == 0) ? spatHW : (spatHW + nd2);
            const float arg  = __builtin_fmaf(di, -0.5f * di, spat);
            const float k    = __expf(arg);
            const float t    = 1.0f - __builtin_fmaf(f.x, y0c, f.y * y1c);
            acc += inb ? (k * t) : 0.0f;
        }
    };

    // 24 (dh,dw) half-pairs: idx 0..2 -> (0, idx+1); idx 3..23 -> (1+(idx-3)/7, (idx-3)%7-3)
    const int base = sub * 3;
    #pragma unroll
    for (int j = 0; j < 3; ++j) {
        const int idx = base + j;
        int dh, dw;
        if (idx < 3) { dh = 0; dw = idx + 1; }
        else { const int t = idx - 3; dh = 1 + t / 7; dw = t % 7 - 3; }
        pair_body(dh, dw);
    }

    if (sub == 0) {
        // lone (0,0,1) half-offset
        const int zz = d + 1;
        const bool inb = zz < ND;
        const int q = (h << 11) + (w << 5) + (inb ? zz : d);
        const float4 f = ws4[q];
        const float di  = f.z - ic;
        const float arg = __builtin_fmaf(di, -0.5f * di, nd2);
        const float k   = __expf(arg);
        const float t   = 1.0f - __builtin_fmaf(f.x, y0c, f.y * y1c);
        acc += inb ? (k * t) : 0.0f;
    } else if (sub == 7) {
        // out-of-bounds taps, closed form
        const int nhv = min(h, 3) + min(NH - 1 - h, 3) + 1;
        const int nwv = min(w, 3) + min(NW - 1 - w, 3) + 1;
        const int ndv = min(d, 1) + min(ND - 1 - d, 1) + 1;
        const int cnt = 147 - nhv * nwv * ndv;
        const float argo = nh2 * (float)(h * h) + nw2 * (float)(w * w)
                         + nd2 * (float)(d * d) - 0.5f * ic * ic;
        extra = (float)cnt * __expf(argo);
    }

    float contrib = __builtin_fmaf(2.0f, acc, extra);

    // wave64 reduction -> LDS -> one atomic per block
    #pragma unroll
    for (int off = 32; off > 0; off >>= 1)
        contrib += __shfl_down(contrib, off, 64);

    __shared__ float red[8];
    if ((tid & 63) == 0) red[tid >> 6] = contrib;
    __syncthreads();
    if (tid == 0) {
        const float s = red[0] + red[1] + red[2] + red[3]
                      + red[4] + red[5] + red[6] + red[7];
        atomicAdd(out, s * (1.0f / (float)LTOT));
    }
}

extern "C" void kernel_launch(void* const* d_in, const int* in_sizes, int n_in,
                              void* d_out, int out_size, void* d_ws, size_t ws_size,
                              hipStream_t stream) {
    const float* y       = (const float*)d_in[0]; // y_hat_softmax (1,2,64,64,32)
    const float* sample  = (const float*)d_in[1]; // (1,1,64,64,32)
    const float* spacing = (const float*)d_in[2]; // (3,1)
    float* out = (float*)d_out;
    float4* ws4 = (float4*)d_ws;                  // 131072 * 16 B = 2 MB

    hipMemsetAsync(out, 0, sizeof(float), stream);

    pack_kernel<<<LTOT / 256, 256, 0, stream>>>(y, sample, ws4);
    gatedcrf3d_kernel<<<LTOT / 64, 512, 0, stream>>>(ws4, spacing, out);
}

// Round 4
// 74.246 us; speedup vs baseline: 1.1940x; 1.1940x over previous
//
#include <hip/hip_runtime.h>

// Problem constants
#define NH 64
#define NW 64
#define ND 32
#define LTOT (NH * NW * ND)   // 131072

// Symmetric-pair formulation (verified exact in R2/R3):
//   loss * L = sum_{unordered in-bounds pairs (p,q), 7x7x3 nbhd} 2*k_pq*(1 - y0p*y0q - y1p*y1q)
//            + sum_p (147 - nh*nw*nd) * k_oob(p)
// k_oob(p) = exp(-0.5*||center feats||^2)  (zero-padded unfold semantics).
// 73 half-offsets = 24 (dh,dw) pairs x dd in {-1,0,1}  +  the lone (0,0,1).
// 8 wave-uniform subsets x 3 pairs each; sub0 adds the lone tap, sub7 the OOB term.
// __launch_bounds__(1024,8): force VGPR<=64 -> 32 waves/CU resident (the 64-VGPR cliff).

__global__ __launch_bounds__(1024, 8)
void gatedcrf3d_kernel(const float* __restrict__ y,       // (2, L)
                       const float* __restrict__ sample,  // (1, L)
                       const float* __restrict__ spacing, // (3,)
                       float* __restrict__ out)           // (1,) pre-zeroed
{
    const int tid = threadIdx.x;
    const int sub = tid >> 7;                    // 0..7, uniform per wave
    const int v   = tid & 127;                   // voxel slot in block

    const int h = blockIdx.x >> 4;               // provably scalar
    const int w = ((blockIdx.x & 15) << 2) + (v >> 5);
    const int d = v & 31;
    const int p = (h << 11) + (w << 5) + d;      // == blockIdx.x*128 + v

    constexpr float L2E  = 1.4426950408889634f;  // log2(e)
    constexpr float NHL2 = -0.5f * L2E;

    const float sH = spacing[0] * 0.2f;          // / SIGMA_XY
    const float sW = spacing[1] * 0.2f;
    const float sD = spacing[2] * 0.2f;
    const float nh2 = NHL2 * sH * sH;            // -0.5*log2e pre-folded
    const float nw2 = NHL2 * sW * sW;
    const float nd2 = NHL2 * sD * sD;

    const float ic  = sample[p] * 10.0f;         // / SIGMA_IMG
    const float y0c = y[p];
    const float y1c = y[LTOT + p];

    const int  zm = max(d - 1, 0);
    const int  zp = min(d + 1, ND - 1);
    const bool vm = d > 0;
    const bool vp = d < ND - 1;

    float acc = 0.0f, extra = 0.0f;

    auto PB = [&](int dh, int dw) {              // dh,dw are literals -> const-folded
        const int hh = h + dh;                   // dh >= 0 always
        const int ww = w + dw;
        const bool ibhw = (hh < NH) & ((unsigned)ww < NW);
        const int hc = min(hh, NH - 1);
        const int wc = min(max(ww, 0), NW - 1);
        const int qb = (hc << 11) + (wc << 5);
        const float spat0 = nh2 * (float)(dh * dh) + nw2 * (float)(dw * dw);
        const float spat1 = spat0 + nd2;
        const int q0 = qb + zm, q1 = qb + d, q2 = qb + zp;
        // issue all 9 loads up front
        const float s0 = sample[q0], s1 = sample[q1], s2 = sample[q2];
        const float a0 = y[q0],      a1 = y[q1],      a2 = y[q2];
        const float b0 = y[LTOT+q0], b1 = y[LTOT+q1], b2 = y[LTOT+q2];

        float di, arg, k, t;
        di  = __builtin_fmaf(s0, 10.0f, -ic);
        arg = __builtin_fmaf(di * NHL2, di, spat1);
        k   = __builtin_exp2f(arg);
        t   = 1.0f - __builtin_fmaf(a0, y0c, b0 * y1c);
        acc += (ibhw & vm) ? k * t : 0.0f;

        di  = __builtin_fmaf(s1, 10.0f, -ic);
        arg = __builtin_fmaf(di * NHL2, di, spat0);
        k   = __builtin_exp2f(arg);
        t   = 1.0f - __builtin_fmaf(a1, y0c, b1 * y1c);
        acc += ibhw ? k * t : 0.0f;

        di  = __builtin_fmaf(s2, 10.0f, -ic);
        arg = __builtin_fmaf(di * NHL2, di, spat1);
        k   = __builtin_exp2f(arg);
        t   = 1.0f - __builtin_fmaf(a2, y0c, b2 * y1c);
        acc += (ibhw & vp) ? k * t : 0.0f;
    };

    switch (sub) {
      case 0: PB(0,1); PB(0,2); PB(0,3); {
            // lone (0,0,1) half-offset
            const int q = (h << 11) + (w << 5) + zp;
            const float di  = __builtin_fmaf(sample[q], 10.0f, -ic);
            const float arg = __builtin_fmaf(di * NHL2, di, nd2);
            const float k   = __builtin_exp2f(arg);
            const float t   = 1.0f - __builtin_fmaf(y[q], y0c, y[LTOT + q] * y1c);
            acc += vp ? k * t : 0.0f;
        } break;
      case 1: PB(1,-3); PB(1,-2); PB(1,-1); break;
      case 2: PB(1, 0); PB(1, 1); PB(1, 2); break;
      case 3: PB(1, 3); PB(2,-3); PB(2,-2); break;
      case 4: PB(2,-1); PB(2, 0); PB(2, 1); break;
      case 5: PB(2, 2); PB(2, 3); PB(3,-3); break;
      case 6: PB(3,-2); PB(3,-1); PB(3, 0); break;
      case 7: PB(3, 1); PB(3, 2); PB(3, 3); {
            // out-of-bounds taps, closed form
            const int nhv = min(h, 3) + min(NH - 1 - h, 3) + 1;
            const int nwv = min(w, 3) + min(NW - 1 - w, 3) + 1;
            const int ndv = min(d, 1) + min(ND - 1 - d, 1) + 1;
            const int cnt = 147 - nhv * nwv * ndv;
            const float argo = nh2 * (float)(h * h) + nw2 * (float)(w * w)
                             + nd2 * (float)(d * d) + NHL2 * ic * ic;
            extra = (float)cnt * __builtin_exp2f(argo);
        } break;
    }

    float contrib = __builtin_fmaf(2.0f, acc, extra);

    // wave64 reduction -> LDS -> one atomic per block (1024 atomics total, R2-proven)
    #pragma unroll
    for (int off = 32; off > 0; off >>= 1)
        contrib += __shfl_down(contrib, off, 64);

    __shared__ float red[16];
    if ((tid & 63) == 0) red[tid >> 6] = contrib;
    __syncthreads();
    if (tid == 0) {
        float s = 0.0f;
        #pragma unroll
        for (int i = 0; i < 16; ++i) s += red[i];
        atomicAdd(out, s * (1.0f / (float)LTOT));
    }
}

extern "C" void kernel_launch(void* const* d_in, const int* in_sizes, int n_in,
                              void* d_out, int out_size, void* d_ws, size_t ws_size,
                              hipStream_t stream) {
    const float* y       = (const float*)d_in[0]; // y_hat_softmax (1,2,64,64,32)
    const float* sample  = (const float*)d_in[1]; // (1,1,64,64,32)
    const float* spacing = (const float*)d_in[2]; // (3,1)
    float* out = (float*)d_out;

    hipMemsetAsync(out, 0, sizeof(float), stream);

    gatedcrf3d_kernel<<<LTOT / 128, 1024, 0, stream>>>(y, sample, spacing, out);
}